// Round 1
// baseline (540.123 us; speedup 1.0000x reference)
//
#include <hip/hip_runtime.h>

#define BATCH 32
#define LSEQ  4096
#define HDIM  768            // 192 float4 per row
#define NEGV  (-1e30f)

// ---------------------------------------------------------------------------
// Kernel 1: per-row dual dot product. One wave (64 lanes) per row.
// Lane i loads float4 at positions {i, i+64, i+128} of the row (coalesced,
// 16B/lane). W fragments hoisted into registers once per wave (grid-stride
// over rows amortizes the W load).
// ---------------------------------------------------------------------------
__global__ __launch_bounds__(256) void st_kernel(const float* __restrict__ words,
                                                 const float* __restrict__ W,
                                                 float* __restrict__ s_buf,
                                                 float* __restrict__ t_buf,
                                                 int total_rows) {
    const int lane = threadIdx.x & 63;
    const int wave = threadIdx.x >> 6;
    const int wave_global = blockIdx.x * 4 + wave;
    const int total_waves = gridDim.x * 4;

    const float4* Wv = (const float4*)W;            // 384 float4: w1 = [0,192), w2 = [192,384)
    const float4 a0 = Wv[lane];
    const float4 a1 = Wv[lane + 64];
    const float4 a2 = Wv[lane + 128];
    const float4 b0 = Wv[192 + lane];
    const float4 b1 = Wv[192 + lane + 64];
    const float4 b2 = Wv[192 + lane + 128];

    for (int row = wave_global; row < total_rows; row += total_waves) {
        const float4* wp = (const float4*)words + (size_t)row * (HDIM / 4);
        const float4 x0 = wp[lane];
        const float4 x1 = wp[lane + 64];
        const float4 x2 = wp[lane + 128];

        float s = 0.f, t = 0.f;
        s += x0.x * a0.x; s += x0.y * a0.y; s += x0.z * a0.z; s += x0.w * a0.w;
        s += x1.x * a1.x; s += x1.y * a1.y; s += x1.z * a1.z; s += x1.w * a1.w;
        s += x2.x * a2.x; s += x2.y * a2.y; s += x2.z * a2.z; s += x2.w * a2.w;
        t += x0.x * b0.x; t += x0.y * b0.y; t += x0.z * b0.z; t += x0.w * b0.w;
        t += x1.x * b1.x; t += x1.y * b1.y; t += x1.z * b1.z; t += x1.w * b1.w;
        t += x2.x * b2.x; t += x2.y * b2.y; t += x2.z * b2.z; t += x2.w * b2.w;

        // wave-64 tree reduction
        #pragma unroll
        for (int off = 32; off > 0; off >>= 1) {
            s += __shfl_down(s, off, 64);
            t += __shfl_down(t, off, 64);
        }
        if (lane == 0) {
            s_buf[row] = s;
            t_buf[row] = t;
        }
    }
}

// ---------------------------------------------------------------------------
// Kernel 2: per-batch sliding-window max. out[b] = max(0, M + bias) where
// M = max over l, k in [1,5], l+k < L of (s[l] + t[l+k]).
// ---------------------------------------------------------------------------
__global__ __launch_bounds__(256) void max_kernel(const float* __restrict__ s_buf,
                                                  const float* __restrict__ t_buf,
                                                  const float* __restrict__ bias,
                                                  float* __restrict__ out) {
    const int b = blockIdx.x;
    const float* s = s_buf + (size_t)b * LSEQ;
    const float* t = t_buf + (size_t)b * LSEQ;

    float m = NEGV;
    for (int l = threadIdx.x; l < LSEQ; l += 256) {
        float tm = NEGV;
        #pragma unroll
        for (int k = 1; k <= 5; ++k) {
            if (l + k < LSEQ) tm = fmaxf(tm, t[l + k]);
        }
        m = fmaxf(m, s[l] + tm);
    }
    #pragma unroll
    for (int off = 32; off > 0; off >>= 1) {
        m = fmaxf(m, __shfl_down(m, off, 64));
    }
    __shared__ float red[4];
    if ((threadIdx.x & 63) == 0) red[threadIdx.x >> 6] = m;
    __syncthreads();
    if (threadIdx.x == 0) {
        float M = fmaxf(fmaxf(red[0], red[1]), fmaxf(red[2], red[3]));
        out[b] = fmaxf(0.f, M + bias[0]);
    }
}

extern "C" void kernel_launch(void* const* d_in, const int* in_sizes, int n_in,
                              void* d_out, int out_size, void* d_ws, size_t ws_size,
                              hipStream_t stream) {
    const float* words = (const float*)d_in[0];
    // d_in[1] = diff (unused by the reference)
    const float* W    = (const float*)d_in[2];
    const float* bias = (const float*)d_in[3];
    float* out = (float*)d_out;

    float* s_buf = (float*)d_ws;                 // BATCH*LSEQ floats
    float* t_buf = s_buf + BATCH * LSEQ;         // BATCH*LSEQ floats (1 MB total)

    const int total_rows = BATCH * LSEQ;         // 131072 rows
    // 4096 blocks x 4 waves = 16384 waves -> 8 rows per wave
    st_kernel<<<4096, 256, 0, stream>>>(words, W, s_buf, t_buf, total_rows);
    max_kernel<<<BATCH, 256, 0, stream>>>(s_buf, t_buf, bias, out);
}

// Round 2
// 527.991 us; speedup vs baseline: 1.0230x; 1.0230x over previous
//
#include <hip/hip_runtime.h>

#define BATCH 32
#define LSEQ  4096
#define HDIM  768            // 192 float4 per row
#define NEGV  (-1e30f)

// ---------------------------------------------------------------------------
// Kernel 1: per-row dual dot product. 16 lanes per row, 4 rows per wave.
// Lane layout: sub = lane&15 (chunk within row), r = lane>>4 (row in group).
// Each lane accumulates 12 float4 (48 floats) of its row against W fragments
// held in registers, then a 4-step shuffle reduction within the 16-lane group
// (2 cross-lane ops per row vs 12 in the wave-per-row version).
// ---------------------------------------------------------------------------
__global__ __launch_bounds__(256) void st_kernel(const float* __restrict__ words,
                                                 const float* __restrict__ W,
                                                 float* __restrict__ s_buf,
                                                 float* __restrict__ t_buf,
                                                 int total_groups) {
    const int lane = threadIdx.x & 63;
    const int sub  = lane & 15;
    const int r    = lane >> 4;
    const int wave_global = blockIdx.x * 4 + (threadIdx.x >> 6);
    const int total_waves = gridDim.x * 4;

    const float4* Wv = (const float4*)W;   // 384 float4: w1=[0,192), w2=[192,384)
    float4 a[12], b[12];
    #pragma unroll
    for (int j = 0; j < 12; ++j) {
        a[j] = Wv[sub + 16 * j];
        b[j] = Wv[192 + sub + 16 * j];
    }

    for (int g = wave_global; g < total_groups; g += total_waves) {
        const int row = g * 4 + r;
        const float4* wp = (const float4*)words + (size_t)row * (HDIM / 4);
        float s = 0.f, t = 0.f;
        #pragma unroll
        for (int j = 0; j < 12; ++j) {
            const float4 x = wp[sub + 16 * j];
            s += x.x * a[j].x; s += x.y * a[j].y; s += x.z * a[j].z; s += x.w * a[j].w;
            t += x.x * b[j].x; t += x.y * b[j].y; t += x.z * b[j].z; t += x.w * b[j].w;
        }
        #pragma unroll
        for (int off = 8; off > 0; off >>= 1) {
            s += __shfl_down(s, off, 16);
            t += __shfl_down(t, off, 16);
        }
        if (sub == 0) {            // lanes 0,16,32,48 -> s_buf[row..row+3]: coalesced
            s_buf[row] = s;
            t_buf[row] = t;
        }
    }
}

// ---------------------------------------------------------------------------
// Kernel 2: per-batch sliding-window max. out[b] = max(0, M + bias) where
// M = max over l, k in [1,5], l+k < L of (s[l] + t[l+k]).
// ---------------------------------------------------------------------------
__global__ __launch_bounds__(1024) void max_kernel(const float* __restrict__ s_buf,
                                                   const float* __restrict__ t_buf,
                                                   const float* __restrict__ bias,
                                                   float* __restrict__ out) {
    const int b = blockIdx.x;
    const float* s = s_buf + (size_t)b * LSEQ;
    const float* t = t_buf + (size_t)b * LSEQ;

    float m = NEGV;
    for (int l = threadIdx.x; l < LSEQ; l += 1024) {
        float tm = NEGV;
        #pragma unroll
        for (int k = 1; k <= 5; ++k) {
            if (l + k < LSEQ) tm = fmaxf(tm, t[l + k]);
        }
        m = fmaxf(m, s[l] + tm);
    }
    #pragma unroll
    for (int off = 32; off > 0; off >>= 1) {
        m = fmaxf(m, __shfl_down(m, off, 64));
    }
    __shared__ float red[16];
    if ((threadIdx.x & 63) == 0) red[threadIdx.x >> 6] = m;
    __syncthreads();
    if (threadIdx.x == 0) {
        float M = NEGV;
        #pragma unroll
        for (int i = 0; i < 16; ++i) M = fmaxf(M, red[i]);
        out[b] = fmaxf(0.f, M + bias[0]);
    }
}

extern "C" void kernel_launch(void* const* d_in, const int* in_sizes, int n_in,
                              void* d_out, int out_size, void* d_ws, size_t ws_size,
                              hipStream_t stream) {
    const float* words = (const float*)d_in[0];
    // d_in[1] = diff (unused by the reference)
    const float* W    = (const float*)d_in[2];
    const float* bias = (const float*)d_in[3];
    float* out = (float*)d_out;

    float* s_buf = (float*)d_ws;                 // BATCH*LSEQ floats
    float* t_buf = s_buf + BATCH * LSEQ;         // BATCH*LSEQ floats (1 MB total)

    const int total_groups = (BATCH * LSEQ) / 4; // 32768 groups of 4 rows
    // 2048 blocks x 4 waves = 8192 waves -> 4 groups (16 rows) per wave
    st_kernel<<<2048, 256, 0, stream>>>(words, W, s_buf, t_buf, total_groups);
    max_kernel<<<BATCH, 1024, 0, stream>>>(s_buf, t_buf, bias, out);
}